// Round 2
// baseline (19.596 us; speedup 1.0000x reference)
//
#include <hip/hip_runtime.h>

// out[i*1536 + j] = -(1/0.924458) * sum_{a,b} w[a][b] * x[3i+a][3j+b]
// x: 4608x4608 f32, w: 3x3 f32, out: 1536x1536 f32.
//
// LDS-staged version: each 256-thread block computes a 4-row x 256-col output
// tile. Input tile = 12 rows x 768 floats = 2304 float4, staged to LDS with
// fully lane-contiguous global loads (9 float4/thread), then each wave
// computes one output row from LDS (stride-3-float4 reads, gcd(3,8)=1 ->
// conflict-free bank-group permutation).

constexpr int W        = 4608;          // input row stride (floats)
constexpr int NH       = 1536;          // output cols
constexpr int TILE_OR  = 4;             // output rows per block (= waves)
constexpr int TILE_OC  = 256;           // output cols per block
constexpr int IN_ROWS  = 3 * TILE_OR;   // 12
constexpr int IN_COLS  = 3 * TILE_OC;   // 768 floats per input row
constexpr int F4_ROW   = IN_COLS / 4;   // 192 float4 per input row
constexpr int TOTAL_F4 = IN_ROWS * F4_ROW; // 2304
constexpr int BLOCK    = 256;
constexpr int F4_PER_T = TOTAL_F4 / BLOCK; // 9

__global__ __launch_bounds__(BLOCK) void conv3x3_s3_lds(
    const float* __restrict__ x,
    const float* __restrict__ w,
    float* __restrict__ out)
{
    __shared__ float4 lds[TOTAL_F4];   // 36 KB

    const int t    = threadIdx.x;
    const int tile = blockIdx.x;
    constexpr int TILES_PER_ROW = NH / TILE_OC;   // 6
    const int ti = tile / TILES_PER_ROW;          // tile row  [0,384)
    const int tj = tile - ti * TILES_PER_ROW;     // tile col  [0,6)

    const int R0 = ti * IN_ROWS;    // input row base  (= 3 * output row base)
    const int C0 = tj * IN_COLS;    // input col base

    const float* xb = x + (size_t)R0 * W + C0;

    // ---- stage: 9 lane-contiguous float4 loads per thread ----
    float4 tmp[F4_PER_T];
    #pragma unroll
    for (int k = 0; k < F4_PER_T; ++k) {
        const int f = t + k * BLOCK;          // float4 index in tile
        const int r = f / F4_ROW;             // const-divide -> magic mul
        const int c = f - r * F4_ROW;
        tmp[k] = *reinterpret_cast<const float4*>(xb + (size_t)r * W + 4 * c);
    }

    // uniform scalar weight loads (overlap with global loads)
    const float w00 = w[0], w01 = w[1], w02 = w[2];
    const float w10 = w[3], w11 = w[4], w12 = w[5];
    const float w20 = w[6], w21 = w[7], w22 = w[8];

    #pragma unroll
    for (int k = 0; k < F4_PER_T; ++k)
        lds[t + k * BLOCK] = tmp[k];

    __syncthreads();

    // ---- compute: wave wv handles output row (4*ti + wv) ----
    const int wv = t >> 6;     // wave id = local output row [0,4)
    const int l  = t & 63;     // lane    = output quad      [0,64)

    const float* lf = reinterpret_cast<const float*>(lds);

    float acc0 = 0.f, acc1 = 0.f, acc2 = 0.f, acc3 = 0.f;

    #pragma unroll
    for (int a = 0; a < 3; ++a) {
        const float* row = lf + (size_t)(3 * wv + a) * IN_COLS + 12 * l;
        const float4 v0 = *reinterpret_cast<const float4*>(row);
        const float4 v1 = *reinterpret_cast<const float4*>(row + 4);
        const float4 v2 = *reinterpret_cast<const float4*>(row + 8);

        float wa0, wa1, wa2;
        if (a == 0)      { wa0 = w00; wa1 = w01; wa2 = w02; }
        else if (a == 1) { wa0 = w10; wa1 = w11; wa2 = w12; }
        else             { wa0 = w20; wa1 = w21; wa2 = w22; }

        acc0 += wa0 * v0.x + wa1 * v0.y + wa2 * v0.z;
        acc1 += wa0 * v0.w + wa1 * v1.x + wa2 * v1.y;
        acc2 += wa0 * v1.z + wa1 * v1.w + wa2 * v2.x;
        acc3 += wa0 * v2.y + wa1 * v2.z + wa2 * v2.w;
    }

    const float scale = -1.0f / 0.924458f;
    float4 r4;
    r4.x = acc0 * scale;
    r4.y = acc1 * scale;
    r4.z = acc2 * scale;
    r4.w = acc3 * scale;

    float* o = out + (size_t)(TILE_OR * ti + wv) * NH + TILE_OC * tj + 4 * l;
    *reinterpret_cast<float4*>(o) = r4;
}

extern "C" void kernel_launch(void* const* d_in, const int* in_sizes, int n_in,
                              void* d_out, int out_size, void* d_ws, size_t ws_size,
                              hipStream_t stream)
{
    const float* x = (const float*)d_in[0];   // 4608*4608
    const float* w = (const float*)d_in[1];   // 9
    float* out = (float*)d_out;               // 1536*1536

    constexpr int GRID = (NH / TILE_OR) * (NH / TILE_OC); // 384 * 6 = 2304
    conv3x3_s3_lds<<<GRID, BLOCK, 0, stream>>>(x, w, out);
}